// Round 12
// baseline (291.605 us; speedup 1.0000x reference)
//
#include <hip/hip_runtime.h>

#define NA 5
#define LL 500
#define DD 300
#define H1 10
#define H2 50
#define NB 256
#define ADS 11   // LDS row stride (odd -> conflict-free column access)

// k_proj2: one block per (side, b, l-half) = 1024 blocks x 512 threads.
// Thread = (cs, lpos): cs = tid>>8 picks channel half (25 accs, r10-proven
// bitwise chains), l = lhalf*256 + (tid&255). Both cs-threads of a token
// are in the SAME block -> same L1 -> gather fetched once (r10's mistake
// was cs-halves on different XCDs -> 2x HBM fetch). ~60 unified regs ->
// 7-8 waves/SIMD eligible; 2x threads per token doubles gather MLP.

__global__ __launch_bounds__(512, 1)
void k_proj2(const int* __restrict__ Uids, const int* __restrict__ Iids,
             const int* __restrict__ Udocs, const int* __restrict__ Idocs,
             const float* __restrict__ Wemb,
             const float* __restrict__ AP,   // [A][D][H1]
             float* __restrict__ adocG)      // [2*NB][LL][50]
{
    const int tid   = threadIdx.x;
    const int bid   = blockIdx.x;
    const int lhalf = bid & 1;
    const int sb    = bid >> 1;        // side*NB + b
    const int side  = sb >> 8;
    const int b     = sb & 255;
    const int cs    = tid >> 8;        // 0 -> c0..24, 1 -> c25..49
    const int l     = lhalf * 256 + (tid & 255);

    const int* ids  = side ? Iids : Uids;
    const int* docs = side ? Idocs : Udocs;
    const int uid = ids[b];
    const int* doc = docs + (long)uid * LL;

    if (l < LL) {
        const int tok = doc[l];
        float acc[25];
        #pragma unroll
        for (int c = 0; c < 25; ++c) acc[c] = 0.f;

        const float4* e4 = (const float4*)(Wemb + (long)tok * DD);
        float4 e0 = e4[0];
        float4 e1 = e4[1];
        for (int db = 0; db < 75; ++db) {
            float4 e2 = e1;
            if (db < 73) e2 = e4[db + 2];
            const float ev0 = e0.x, ev1 = e0.y, ev2 = e0.z, ev3 = e0.w;
            const int d0 = db * 4;
            if (cs == 0) {
                #pragma unroll
                for (int a_ = 0; a_ < 3; ++a_) {
                    const float* wp = AP + a_ * (DD * H1) + d0 * H1;  // uniform -> s_load
                    const int hn = (a_ == 2) ? 5 : H1;
                    #pragma unroll
                    for (int h = 0; h < H1; ++h) {
                        if (h < hn)
                            acc[a_ * H1 + h] += ev0 * wp[h] + ev1 * wp[H1 + h]
                                              + ev2 * wp[2 * H1 + h] + ev3 * wp[3 * H1 + h];
                    }
                }
            } else {
                #pragma unroll
                for (int a_ = 2; a_ < 5; ++a_) {
                    const float* wp = AP + a_ * (DD * H1) + d0 * H1;
                    const int h0 = (a_ == 2) ? 5 : 0;
                    #pragma unroll
                    for (int h = 0; h < H1; ++h) {
                        if (h >= h0)
                            acc[a_ * H1 + h - 25] += ev0 * wp[h] + ev1 * wp[H1 + h]
                                                   + ev2 * wp[2 * H1 + h] + ev3 * wp[3 * H1 + h];
                    }
                }
            }
            e0 = e1; e1 = e2;
        }

        float* out = adocG + ((long)sb * LL + l) * 50 + cs * 25;
        #pragma unroll
        for (int c = 0; c < 25; ++c) out[c] = acc[c];
    }
}

__global__ __launch_bounds__(64)
void k_attn(const float* __restrict__ adocG,
            const float* __restrict__ AE,   // [A][30]
            float* __restrict__ Rep)        // [2][NB][A][H1]
{
    __shared__ float stripe[LL][ADS];
    __shared__ float lg[LL];

    const int bid  = blockIdx.x;       // sb*NA + a
    const int a_   = bid % NA;
    const int sb   = bid / NA;
    const int lane = threadIdx.x;

    for (int l = lane; l < LL; l += 64) {
        const float* src = adocG + ((long)sb * LL + l) * 50 + a_ * H1;
        #pragma unroll
        for (int h = 0; h < H1; ++h) stripe[l][h] = src[h];
    }
    __syncthreads();

    // window logits (round-9/10 exact chain, strided by 64)
    const float* aerow = AE + a_ * 30;   // uniform -> s_load
    for (int l = lane; l < LL; l += 64) {
        float s = 0.f;
        if (l > 0) {
            const float* ad = &stripe[l - 1][0];
            #pragma unroll
            for (int h = 0; h < H1; ++h) s += ad[h] * aerow[h];
        }
        {
            const float* ad = &stripe[l][0];
            #pragma unroll
            for (int h = 0; h < H1; ++h) s += ad[h] * aerow[H1 + h];
        }
        if (l < LL - 1) {
            const float* ad = &stripe[l + 1][0];
            #pragma unroll
            for (int h = 0; h < H1; ++h) s += ad[h] * aerow[2 * H1 + h];
        }
        lg[l] = s;
    }
    __syncthreads();

    // softmax over L + weighted sum (round-9/10 exact reduction)
    float mx = -1e30f;
    for (int p = lane; p < LL; p += 64) mx = fmaxf(mx, lg[p]);
    #pragma unroll
    for (int o = 32; o; o >>= 1) mx = fmaxf(mx, __shfl_xor(mx, o, 64));
    float sum = 0.f;
    for (int p = lane; p < LL; p += 64) {
        float pr = expf(lg[p] - mx);
        lg[p] = pr;
        sum += pr;
    }
    #pragma unroll
    for (int o = 32; o; o >>= 1) sum += __shfl_xor(sum, o, 64);
    float r[H1];
    #pragma unroll
    for (int h = 0; h < H1; ++h) r[h] = 0.f;
    for (int p = lane; p < LL; p += 64) {
        const float pr = lg[p];
        const float* ad = &stripe[p][0];
        #pragma unroll
        for (int h = 0; h < H1; ++h) r[h] += pr * ad[h];
    }
    #pragma unroll
    for (int h = 0; h < H1; ++h) {
        #pragma unroll
        for (int o = 32; o; o >>= 1) r[h] += __shfl_xor(r[h], o, 64);
    }
    if (lane == 0) {
        const float inv = 1.f / sum;
        float* out = Rep + ((long)sb * NA + a_) * H1;
        #pragma unroll
        for (int h = 0; h < H1; ++h) out[h] = r[h] * inv;
    }
}

// ---------------- fallback fused path (round 9/11, 165 us) ----------------
__global__ __launch_bounds__(512, 1)
void k_aspect(const int* __restrict__ Uids, const int* __restrict__ Iids,
              const int* __restrict__ Udocs, const int* __restrict__ Idocs,
              const float* __restrict__ Wemb,
              const float* __restrict__ AE,
              const float* __restrict__ AP,
              float* __restrict__ Rep)
{
    __shared__ float adoc[LL][ADS];
    __shared__ float lg[LL];

    const int tid  = threadIdx.x;
    const int bid  = blockIdx.x;
    const int side = bid >> 8;
    const int b    = bid & 255;

    const int* ids  = side ? Iids : Uids;
    const int* docs = side ? Idocs : Udocs;

    const int uid = ids[b];
    const int* doc = docs + (long)uid * LL;

    float acc[NA * H1];
    #pragma unroll
    for (int c = 0; c < NA * H1; ++c) acc[c] = 0.f;

    if (tid < LL) {
        const int tok = doc[tid];
        const float4* e4 = (const float4*)(Wemb + (long)tok * DD);
        float4 e0 = e4[0];
        float4 e1 = e4[1];
        for (int db = 0; db < 75; ++db) {
            float4 e2 = e1;
            if (db < 73) e2 = e4[db + 2];
            const float ev0 = e0.x, ev1 = e0.y, ev2 = e0.z, ev3 = e0.w;
            const int d0 = db * 4;
            #pragma unroll
            for (int a_ = 0; a_ < NA; ++a_) {
                const float* wp = AP + a_ * (DD * H1) + d0 * H1;
                #pragma unroll
                for (int h = 0; h < H1; ++h) {
                    acc[a_ * H1 + h] += ev0 * wp[h] + ev1 * wp[H1 + h]
                                      + ev2 * wp[2 * H1 + h] + ev3 * wp[3 * H1 + h];
                }
            }
            e0 = e1; e1 = e2;
        }
    }

    #pragma unroll
    for (int a_ = 0; a_ < NA; ++a_) {
        if (tid < LL) {
            #pragma unroll
            for (int h = 0; h < H1; ++h) adoc[tid][h] = acc[a_ * H1 + h];
        }
        __syncthreads();

        if (tid < LL) {
            const float* aerow = AE + a_ * 30;
            float s = 0.f;
            if (tid > 0) {
                const float* ad = &adoc[tid - 1][0];
                #pragma unroll
                for (int h = 0; h < H1; ++h) s += ad[h] * aerow[h];
            }
            {
                const float* ad = &adoc[tid][0];
                #pragma unroll
                for (int h = 0; h < H1; ++h) s += ad[h] * aerow[H1 + h];
            }
            if (tid < LL - 1) {
                const float* ad = &adoc[tid + 1][0];
                #pragma unroll
                for (int h = 0; h < H1; ++h) s += ad[h] * aerow[2 * H1 + h];
            }
            lg[tid] = s;
        }
        __syncthreads();

        if (tid < 64) {
            const int lane = tid;
            float mx = -1e30f;
            for (int p = lane; p < LL; p += 64) mx = fmaxf(mx, lg[p]);
            #pragma unroll
            for (int o = 32; o; o >>= 1) mx = fmaxf(mx, __shfl_xor(mx, o, 64));
            float sum = 0.f;
            for (int p = lane; p < LL; p += 64) {
                float pr = expf(lg[p] - mx);
                lg[p] = pr;
                sum += pr;
            }
            #pragma unroll
            for (int o = 32; o; o >>= 1) sum += __shfl_xor(sum, o, 64);
            float r[H1];
            #pragma unroll
            for (int h = 0; h < H1; ++h) r[h] = 0.f;
            for (int p = lane; p < LL; p += 64) {
                const float pr = lg[p];
                const float* ad = &adoc[p][0];
                #pragma unroll
                for (int h = 0; h < H1; ++h) r[h] += pr * ad[h];
            }
            #pragma unroll
            for (int h = 0; h < H1; ++h) {
                #pragma unroll
                for (int o = 32; o; o >>= 1) r[h] += __shfl_xor(r[h], o, 64);
            }
            if (lane == 0) {
                const float inv = 1.f / sum;
                float* out = Rep + (((long)side * NB + b) * NA + a_) * H1;
                #pragma unroll
                for (int h = 0; h < H1; ++h) out[h] = r[h] * inv;
            }
        }
        __syncthreads();
    }
}

__global__ __launch_bounds__(64)
void k_final(const float* __restrict__ Rep, const int* __restrict__ Uids,
             const int* __restrict__ Iids, const float* __restrict__ M,
             const float* __restrict__ Uproj, const float* __restrict__ Uw,
             const float* __restrict__ Iproj, const float* __restrict__ Iw,
             const float* __restrict__ Bu, const float* __restrict__ Bi,
             const float* __restrict__ Bg, float* __restrict__ out)
{
    __shared__ float Ud[50], Idd[50], tmp[50], aff[25];
    const int b = blockIdx.x, lane = threadIdx.x;
    if (lane < 50) {
        Ud[lane]  = Rep[(long)b * 50 + lane];
        Idd[lane] = Rep[(long)NB * 50 + (long)b * 50 + lane];
    }
    __syncthreads();
    if (lane < 50) {  // tmp[c][h] = sum_k M[h][k] * Id[c][k]
        const int c = lane / 10, h = lane % 10;
        float t = 0.f;
        #pragma unroll
        for (int k = 0; k < 10; ++k) t += M[h * 10 + k] * Idd[c * 10 + k];
        tmp[lane] = t;
    }
    __syncthreads();
    if (lane < 25) {  // aff[a][c] = relu(sum_h Ud[a][h] * tmp[c][h])
        const int a_ = lane / 5, c = lane % 5;
        float s = 0.f;
        #pragma unroll
        for (int h = 0; h < 10; ++h) s += Ud[a_ * 10 + h] * tmp[c * 10 + h];
        aff[lane] = fmaxf(s, 0.f);
    }
    __syncthreads();

    float hu1[5], hi1[5], tu[5], ti[5];
    if (lane < 50) {
        #pragma unroll
        for (int a_ = 0; a_ < 5; ++a_) {
            float su = 0.f, si = 0.f;
            #pragma unroll
            for (int h = 0; h < 10; ++h) {
                su += Uproj[lane * 10 + h] * Ud[a_ * 10 + h];
                si += Iproj[lane * 10 + h] * Idd[a_ * 10 + h];
            }
            hu1[a_] = su; hi1[a_] = si;
        }
    } else {
        #pragma unroll
        for (int a_ = 0; a_ < 5; ++a_) { hu1[a_] = 0.f; hi1[a_] = 0.f; }
    }
    const float uw = (lane < 50) ? Uw[lane] : 0.f;
    const float iw = (lane < 50) ? Iw[lane] : 0.f;
    #pragma unroll
    for (int a_ = 0; a_ < 5; ++a_) {
        float hu = hu1[a_], hi = hi1[a_];
        #pragma unroll
        for (int c = 0; c < 5; ++c) {
            hu += hi1[c] * aff[a_ * 5 + c];
            hi += hu1[c] * aff[c * 5 + a_];
        }
        tu[a_] = uw * fmaxf(hu, 0.f);
        ti[a_] = iw * fmaxf(hi, 0.f);
    }
    #pragma unroll
    for (int a_ = 0; a_ < 5; ++a_) {
        #pragma unroll
        for (int o = 32; o; o >>= 1) {
            tu[a_] += __shfl_xor(tu[a_], o, 64);
            ti[a_] += __shfl_xor(ti[a_], o, 64);
        }
    }
    if (lane == 0) {
        float mu = tu[0], mi = ti[0];
        #pragma unroll
        for (int a_ = 1; a_ < 5; ++a_) { mu = fmaxf(mu, tu[a_]); mi = fmaxf(mi, ti[a_]); }
        float eu[5], ei[5], su = 0.f, si = 0.f;
        #pragma unroll
        for (int a_ = 0; a_ < 5; ++a_) {
            eu[a_] = expf(tu[a_] - mu); su += eu[a_];
            ei[a_] = expf(ti[a_] - mi); si += ei[a_];
        }
        float R = 0.f;
        #pragma unroll
        for (int a_ = 0; a_ < 5; ++a_) {
            float ar = 0.f;
            #pragma unroll
            for (int h = 0; h < 10; ++h) ar += Ud[a_ * 10 + h] * Idd[a_ * 10 + h];
            R += (eu[a_] / su) * (ei[a_] / si) * ar;
        }
        R += Bu[Uids[b]] + Bi[Iids[b]] + Bg[0];
        out[b] = R;
    }
}

extern "C" void kernel_launch(void* const* d_in, const int* in_sizes, int n_in,
                              void* d_out, int out_size, void* d_ws, size_t ws_size,
                              hipStream_t stream)
{
    const int*   Uids  = (const int*)d_in[0];
    const int*   Iids  = (const int*)d_in[1];
    const int*   Udocs = (const int*)d_in[2];
    const int*   Idocs = (const int*)d_in[3];
    const float* Wemb  = (const float*)d_in[4];
    const float* AE    = (const float*)d_in[5];
    const float* AP    = (const float*)d_in[6];
    const float* M     = (const float*)d_in[7];
    const float* Uproj = (const float*)d_in[8];
    const float* Uw    = (const float*)d_in[9];
    const float* Iproj = (const float*)d_in[10];
    const float* Iw    = (const float*)d_in[11];
    const float* Bu    = (const float*)d_in[12];
    const float* Bi    = (const float*)d_in[13];
    const float* Bg    = (const float*)d_in[14];

    float* Rep = (float*)d_ws;                              // 102400 B
    float* out = (float*)d_out;
    const size_t REP_BYTES  = (size_t)2 * NB * NA * H1 * 4;
    const size_t ADOC_BYTES = (size_t)2 * NB * LL * 50 * 4; // 51.2 MB
    if (ws_size >= REP_BYTES + ADOC_BYTES) {
        float* adocG = (float*)((char*)d_ws + REP_BYTES);
        k_proj2<<<2 * NB * 2, 512, 0, stream>>>(Uids, Iids, Udocs, Idocs, Wemb, AP, adocG);
        k_attn<<<2 * NB * NA, 64, 0, stream>>>(adocG, AE, Rep);
    } else {
        k_aspect<<<2 * NB, 512, 0, stream>>>(Uids, Iids, Udocs, Idocs, Wemb, AE, AP, Rep);
    }
    k_final<<<NB, 64, 0, stream>>>(Rep, Uids, Iids, M, Uproj, Uw, Iproj, Iw, Bu, Bi, Bg, out);
}

// Round 13
// 290.201 us; speedup vs baseline: 1.0048x; 1.0048x over previous
//
#include <hip/hip_runtime.h>

#define NA 5
#define LL 500
#define DD 300
#define H1 10
#define H2 50
#define NB 256
#define ADS 11   // adoc LDS row stride (odd -> conflict-free column access)

// One block per (side, batch): grid = 512, 512 threads, thread = position.
// ROUND-13 CHANGE: AP (5x300x10 = 60 KB) is staged into LDS once per block
// and read via wave-uniform ds_read broadcasts. Rationale: r9/r11/r12 all
// pinned at VALUBusy ~30% / ~800 GB/s effective gather regardless of
// occupancy, prefetch depth, or thread count -> correlated stalls on the
// SHARED scalar path (every wave s_loads the full 60 KB AP per K-walk
// through a ~16 KB cluster-shared K$). LDS is per-CU with broadcast reads.
// FP chains verbatim r9 (absmax 0.0). LDS 84 KB -> 1 block/CU.

__global__ __launch_bounds__(512, 1)
void k_aspect(const int* __restrict__ Uids, const int* __restrict__ Iids,
              const int* __restrict__ Udocs, const int* __restrict__ Idocs,
              const float* __restrict__ Wemb,
              const float* __restrict__ AE,   // [A][30]
              const float* __restrict__ AP,   // [A][D][H1]
              float* __restrict__ Rep)        // [2][B][A][H1]
{
    extern __shared__ char smem[];
    float* apS = (float*)smem;                                  // 15000 f = 60000 B
    float (*adoc)[ADS] = (float(*)[ADS])(smem + 60000);         // 22000 B
    float* lg = (float*)(smem + 60000 + 22000);                 // 2000 B

    const int tid  = threadIdx.x;
    const int bid  = blockIdx.x;
    const int side = bid >> 8;
    const int b    = bid & 255;

    const int* ids  = side ? Iids : Uids;
    const int* docs = side ? Idocs : Udocs;

    const int uid = ids[b];
    const int* doc = docs + (long)uid * LL;

    // ---- stage AP into LDS (vector path, once per block) ----
    {
        const float4* src = (const float4*)AP;      // 15000 floats = 3750 float4
        float4* dst = (float4*)apS;
        for (int i = tid; i < 3750; i += 512) dst[i] = src[i];
    }
    __syncthreads();

    // ---- phase 1: all 50 channels per thread, registers only ----
    float acc[NA * H1];
    #pragma unroll
    for (int c = 0; c < NA * H1; ++c) acc[c] = 0.f;

    if (tid < LL) {
        const int tok = doc[tid];                       // coalesced direct read
        const float4* e4 = (const float4*)(Wemb + (long)tok * DD);
        float4 e0 = e4[0];
        float4 e1 = e4[1];
        for (int db = 0; db < 75; ++db) {
            float4 e2 = e1;
            if (db < 73) e2 = e4[db + 2];               // 2-deep prefetch
            const float ev0 = e0.x, ev1 = e0.y, ev2 = e0.z, ev3 = e0.w;
            const int d0 = db * 4;
            #pragma unroll
            for (int a_ = 0; a_ < NA; ++a_) {
                const float* wp = apS + a_ * (DD * H1) + d0 * H1;  // uniform -> ds broadcast
                #pragma unroll
                for (int h = 0; h < H1; ++h) {
                    acc[a_ * H1 + h] += ev0 * wp[h] + ev1 * wp[H1 + h]
                                      + ev2 * wp[2 * H1 + h] + ev3 * wp[3 * H1 + h];
                }
            }
            e0 = e1; e1 = e2;
        }
    }

    // ---- phase 2: one aspect at a time through LDS (round-9 verbatim) ----
    #pragma unroll
    for (int a_ = 0; a_ < NA; ++a_) {
        __syncthreads();   // apS reads done / previous aspect done
        if (tid < LL) {
            #pragma unroll
            for (int h = 0; h < H1; ++h) adoc[tid][h] = acc[a_ * H1 + h];
        }
        __syncthreads();

        // window logits (round-9 exact chain)
        if (tid < LL) {
            const float* aerow = AE + a_ * 30;       // uniform -> s_load (600 B total, hot)
            float s = 0.f;
            if (tid > 0) {
                const float* ad = &adoc[tid - 1][0];
                #pragma unroll
                for (int h = 0; h < H1; ++h) s += ad[h] * aerow[h];
            }
            {
                const float* ad = &adoc[tid][0];
                #pragma unroll
                for (int h = 0; h < H1; ++h) s += ad[h] * aerow[H1 + h];
            }
            if (tid < LL - 1) {
                const float* ad = &adoc[tid + 1][0];
                #pragma unroll
                for (int h = 0; h < H1; ++h) s += ad[h] * aerow[2 * H1 + h];
            }
            lg[tid] = s;
        }
        __syncthreads();

        // softmax over L + weighted sum (wave 0; round-9 exact reduction)
        if (tid < 64) {
            const int lane = tid;
            float mx = -1e30f;
            for (int p = lane; p < LL; p += 64) mx = fmaxf(mx, lg[p]);
            #pragma unroll
            for (int o = 32; o; o >>= 1) mx = fmaxf(mx, __shfl_xor(mx, o, 64));
            float sum = 0.f;
            for (int p = lane; p < LL; p += 64) {
                float pr = expf(lg[p] - mx);
                lg[p] = pr;
                sum += pr;
            }
            #pragma unroll
            for (int o = 32; o; o >>= 1) sum += __shfl_xor(sum, o, 64);
            float r[H1];
            #pragma unroll
            for (int h = 0; h < H1; ++h) r[h] = 0.f;
            for (int p = lane; p < LL; p += 64) {
                const float pr = lg[p];
                const float* ad = &adoc[p][0];
                #pragma unroll
                for (int h = 0; h < H1; ++h) r[h] += pr * ad[h];
            }
            #pragma unroll
            for (int h = 0; h < H1; ++h) {
                #pragma unroll
                for (int o = 32; o; o >>= 1) r[h] += __shfl_xor(r[h], o, 64);
            }
            if (lane == 0) {
                const float inv = 1.f / sum;
                float* out = Rep + (((long)side * NB + b) * NA + a_) * H1;
                #pragma unroll
                for (int h = 0; h < H1; ++h) out[h] = r[h] * inv;
            }
        }
    }
}

__global__ __launch_bounds__(64)
void k_final(const float* __restrict__ Rep, const int* __restrict__ Uids,
             const int* __restrict__ Iids, const float* __restrict__ M,
             const float* __restrict__ Uproj, const float* __restrict__ Uw,
             const float* __restrict__ Iproj, const float* __restrict__ Iw,
             const float* __restrict__ Bu, const float* __restrict__ Bi,
             const float* __restrict__ Bg, float* __restrict__ out)
{
    __shared__ float Ud[50], Idd[50], tmp[50], aff[25];
    const int b = blockIdx.x, lane = threadIdx.x;
    if (lane < 50) {
        Ud[lane]  = Rep[(long)b * 50 + lane];
        Idd[lane] = Rep[(long)NB * 50 + (long)b * 50 + lane];
    }
    __syncthreads();
    if (lane < 50) {  // tmp[c][h] = sum_k M[h][k] * Id[c][k]
        const int c = lane / 10, h = lane % 10;
        float t = 0.f;
        #pragma unroll
        for (int k = 0; k < 10; ++k) t += M[h * 10 + k] * Idd[c * 10 + k];
        tmp[lane] = t;
    }
    __syncthreads();
    if (lane < 25) {  // aff[a][c] = relu(sum_h Ud[a][h] * tmp[c][h])
        const int a_ = lane / 5, c = lane % 5;
        float s = 0.f;
        #pragma unroll
        for (int h = 0; h < 10; ++h) s += Ud[a_ * 10 + h] * tmp[c * 10 + h];
        aff[lane] = fmaxf(s, 0.f);
    }
    __syncthreads();

    float hu1[5], hi1[5], tu[5], ti[5];
    if (lane < 50) {
        #pragma unroll
        for (int a_ = 0; a_ < 5; ++a_) {
            float su = 0.f, si = 0.f;
            #pragma unroll
            for (int h = 0; h < 10; ++h) {
                su += Uproj[lane * 10 + h] * Ud[a_ * 10 + h];
                si += Iproj[lane * 10 + h] * Idd[a_ * 10 + h];
            }
            hu1[a_] = su; hi1[a_] = si;
        }
    } else {
        #pragma unroll
        for (int a_ = 0; a_ < 5; ++a_) { hu1[a_] = 0.f; hi1[a_] = 0.f; }
    }
    const float uw = (lane < 50) ? Uw[lane] : 0.f;
    const float iw = (lane < 50) ? Iw[lane] : 0.f;
    #pragma unroll
    for (int a_ = 0; a_ < 5; ++a_) {
        float hu = hu1[a_], hi = hi1[a_];
        #pragma unroll
        for (int c = 0; c < 5; ++c) {
            hu += hi1[c] * aff[a_ * 5 + c];   // Hu[e][a] += Hi1[e][c]*aff[a][c]
            hi += hu1[c] * aff[c * 5 + a_];   // Hi[e][c] += Hu1[e][a]*aff[a][c]
        }
        tu[a_] = uw * fmaxf(hu, 0.f);
        ti[a_] = iw * fmaxf(hi, 0.f);
    }
    #pragma unroll
    for (int a_ = 0; a_ < 5; ++a_) {
        #pragma unroll
        for (int o = 32; o; o >>= 1) {
            tu[a_] += __shfl_xor(tu[a_], o, 64);
            ti[a_] += __shfl_xor(ti[a_], o, 64);
        }
    }
    if (lane == 0) {
        float mu = tu[0], mi = ti[0];
        #pragma unroll
        for (int a_ = 1; a_ < 5; ++a_) { mu = fmaxf(mu, tu[a_]); mi = fmaxf(mi, ti[a_]); }
        float eu[5], ei[5], su = 0.f, si = 0.f;
        #pragma unroll
        for (int a_ = 0; a_ < 5; ++a_) {
            eu[a_] = expf(tu[a_] - mu); su += eu[a_];
            ei[a_] = expf(ti[a_] - mi); si += ei[a_];
        }
        float R = 0.f;
        #pragma unroll
        for (int a_ = 0; a_ < 5; ++a_) {
            float ar = 0.f;
            #pragma unroll
            for (int h = 0; h < 10; ++h) ar += Ud[a_ * 10 + h] * Idd[a_ * 10 + h];
            R += (eu[a_] / su) * (ei[a_] / si) * ar;
        }
        R += Bu[Uids[b]] + Bi[Iids[b]] + Bg[0];
        out[b] = R;
    }
}

extern "C" void kernel_launch(void* const* d_in, const int* in_sizes, int n_in,
                              void* d_out, int out_size, void* d_ws, size_t ws_size,
                              hipStream_t stream)
{
    const int*   Uids  = (const int*)d_in[0];
    const int*   Iids  = (const int*)d_in[1];
    const int*   Udocs = (const int*)d_in[2];
    const int*   Idocs = (const int*)d_in[3];
    const float* Wemb  = (const float*)d_in[4];
    const float* AE    = (const float*)d_in[5];
    const float* AP    = (const float*)d_in[6];
    const float* M     = (const float*)d_in[7];
    const float* Uproj = (const float*)d_in[8];
    const float* Uw    = (const float*)d_in[9];
    const float* Iproj = (const float*)d_in[10];
    const float* Iw    = (const float*)d_in[11];
    const float* Bu    = (const float*)d_in[12];
    const float* Bi    = (const float*)d_in[13];
    const float* Bg    = (const float*)d_in[14];

    float* Rep = (float*)d_ws;        // [2][256][5][10] = 102400 B
    float* out = (float*)d_out;

    const size_t smem = 60000 + 22000 + 2000;   // apS + adoc + lg = 84000 B
    k_aspect<<<2 * NB, 512, smem, stream>>>(Uids, Iids, Udocs, Idocs, Wemb, AE, AP, Rep);
    k_final<<<NB, 64, 0, stream>>>(Rep, Uids, Iids, M, Uproj, Uw, Iproj, Iw, Bu, Bi, Bg, out);
}

// Round 14
// 253.847 us; speedup vs baseline: 1.1487x; 1.1432x over previous
//
#include <hip/hip_runtime.h>

#define NA 5
#define LL 500
#define DD 300
#define H1 10
#define H2 50
#define NB 256
#define ADS 11   // adoc LDS row stride (odd -> conflict-free column access)

// One block per (side, batch): grid = 512, 512 threads, thread = position.
// r13 proved LDS-broadcast AP >> scalar-path AP per wave (VALU 37% @ 8
// waves/CU vs 30% @ 15), but 84 KB LDS killed occupancy. r14: K-split AP
// staging into 4 passes (slice <= 15.2 KB) -> LDS 39.2 KB -> 4 blocks/CU
// = 32 waves/CU. Same d-order per channel -> bitwise identical chains.

__global__ __launch_bounds__(512, 1)
void k_aspect(const int* __restrict__ Uids, const int* __restrict__ Iids,
              const int* __restrict__ Udocs, const int* __restrict__ Idocs,
              const float* __restrict__ Wemb,
              const float* __restrict__ AE,   // [A][30]
              const float* __restrict__ AP,   // [A][D][H1]
              float* __restrict__ Rep)        // [2][B][A][H1]
{
    extern __shared__ char smem[];
    float* apS = (float*)smem;                                  // 3800 f = 15200 B
    float (*adoc)[ADS] = (float(*)[ADS])(smem + 15200);         // 22000 B
    float* lg = (float*)(smem + 15200 + 22000);                 // 2000 B

    const int tid  = threadIdx.x;
    const int bid  = blockIdx.x;
    const int side = bid >> 8;
    const int b    = bid & 255;

    const int* ids  = side ? Iids : Uids;
    const int* docs = side ? Idocs : Udocs;

    const int uid = ids[b];
    const int* doc = docs + (long)uid * LL;

    // ---- phase 1: all 50 channels per thread; AP staged per K-slice ----
    float acc[NA * H1];
    #pragma unroll
    for (int c = 0; c < NA * H1; ++c) acc[c] = 0.f;

    const float4* e4 = nullptr;
    float4 e0 = make_float4(0.f, 0.f, 0.f, 0.f);
    float4 e1 = e0;
    if (tid < LL) {
        const int tok = doc[tid];                   // coalesced direct read
        e4 = (const float4*)(Wemb + (long)tok * DD);
        e0 = e4[0];
        e1 = e4[1];
    }

    const int db0s[5] = {0, 19, 38, 57, 75};
    #pragma unroll
    for (int p = 0; p < 4; ++p) {
        const int db0 = db0s[p], db1 = db0s[p + 1];
        const int nf4 = (db1 - db0) * 10;          // float4 per aspect (190 or 180)

        __syncthreads();                            // previous slice fully consumed
        for (int i = tid; i < NA * 190; i += 512) { // stage slice (5 x nf4 float4)
            const int a_ = i / 190, j = i - a_ * 190;
            if (j < nf4) {
                ((float4*)(apS + a_ * 760))[j] =
                    ((const float4*)(AP + a_ * (DD * H1) + db0 * 40))[j];
            }
        }
        __syncthreads();

        if (tid < LL) {
            for (int db = db0; db < db1; ++db) {
                float4 e2 = e1;
                if (db < 73) e2 = e4[db + 2];       // 2-deep prefetch (global bound)
                const float ev0 = e0.x, ev1 = e0.y, ev2 = e0.z, ev3 = e0.w;
                const int o = (db - db0) * 40;
                #pragma unroll
                for (int a_ = 0; a_ < NA; ++a_) {
                    const float* wp = apS + a_ * 760 + o;   // uniform -> ds broadcast
                    #pragma unroll
                    for (int h = 0; h < H1; ++h) {
                        acc[a_ * H1 + h] += ev0 * wp[h] + ev1 * wp[H1 + h]
                                          + ev2 * wp[2 * H1 + h] + ev3 * wp[3 * H1 + h];
                    }
                }
                e0 = e1; e1 = e2;
            }
        }
    }

    // ---- phase 2: one aspect at a time through LDS (r9/r13 verbatim) ----
    #pragma unroll
    for (int a_ = 0; a_ < NA; ++a_) {
        __syncthreads();
        if (tid < LL) {
            #pragma unroll
            for (int h = 0; h < H1; ++h) adoc[tid][h] = acc[a_ * H1 + h];
        }
        __syncthreads();

        // window logits (exact chain)
        if (tid < LL) {
            const float* aerow = AE + a_ * 30;      // uniform -> s_load (600 B, hot)
            float s = 0.f;
            if (tid > 0) {
                const float* ad = &adoc[tid - 1][0];
                #pragma unroll
                for (int h = 0; h < H1; ++h) s += ad[h] * aerow[h];
            }
            {
                const float* ad = &adoc[tid][0];
                #pragma unroll
                for (int h = 0; h < H1; ++h) s += ad[h] * aerow[H1 + h];
            }
            if (tid < LL - 1) {
                const float* ad = &adoc[tid + 1][0];
                #pragma unroll
                for (int h = 0; h < H1; ++h) s += ad[h] * aerow[2 * H1 + h];
            }
            lg[tid] = s;
        }
        __syncthreads();

        // softmax over L + weighted sum (wave 0; exact reduction)
        if (tid < 64) {
            const int lane = tid;
            float mx = -1e30f;
            for (int p = lane; p < LL; p += 64) mx = fmaxf(mx, lg[p]);
            #pragma unroll
            for (int o = 32; o; o >>= 1) mx = fmaxf(mx, __shfl_xor(mx, o, 64));
            float sum = 0.f;
            for (int p = lane; p < LL; p += 64) {
                float pr = expf(lg[p] - mx);
                lg[p] = pr;
                sum += pr;
            }
            #pragma unroll
            for (int o = 32; o; o >>= 1) sum += __shfl_xor(sum, o, 64);
            float r[H1];
            #pragma unroll
            for (int h = 0; h < H1; ++h) r[h] = 0.f;
            for (int p = lane; p < LL; p += 64) {
                const float pr = lg[p];
                const float* ad = &adoc[p][0];
                #pragma unroll
                for (int h = 0; h < H1; ++h) r[h] += pr * ad[h];
            }
            #pragma unroll
            for (int h = 0; h < H1; ++h) {
                #pragma unroll
                for (int o = 32; o; o >>= 1) r[h] += __shfl_xor(r[h], o, 64);
            }
            if (lane == 0) {
                const float inv = 1.f / sum;
                float* out = Rep + (((long)side * NB + b) * NA + a_) * H1;
                #pragma unroll
                for (int h = 0; h < H1; ++h) out[h] = r[h] * inv;
            }
        }
    }
}

__global__ __launch_bounds__(64)
void k_final(const float* __restrict__ Rep, const int* __restrict__ Uids,
             const int* __restrict__ Iids, const float* __restrict__ M,
             const float* __restrict__ Uproj, const float* __restrict__ Uw,
             const float* __restrict__ Iproj, const float* __restrict__ Iw,
             const float* __restrict__ Bu, const float* __restrict__ Bi,
             const float* __restrict__ Bg, float* __restrict__ out)
{
    __shared__ float Ud[50], Idd[50], tmp[50], aff[25];
    const int b = blockIdx.x, lane = threadIdx.x;
    if (lane < 50) {
        Ud[lane]  = Rep[(long)b * 50 + lane];
        Idd[lane] = Rep[(long)NB * 50 + (long)b * 50 + lane];
    }
    __syncthreads();
    if (lane < 50) {  // tmp[c][h] = sum_k M[h][k] * Id[c][k]
        const int c = lane / 10, h = lane % 10;
        float t = 0.f;
        #pragma unroll
        for (int k = 0; k < 10; ++k) t += M[h * 10 + k] * Idd[c * 10 + k];
        tmp[lane] = t;
    }
    __syncthreads();
    if (lane < 25) {  // aff[a][c] = relu(sum_h Ud[a][h] * tmp[c][h])
        const int a_ = lane / 5, c = lane % 5;
        float s = 0.f;
        #pragma unroll
        for (int h = 0; h < 10; ++h) s += Ud[a_ * 10 + h] * tmp[c * 10 + h];
        aff[lane] = fmaxf(s, 0.f);
    }
    __syncthreads();

    float hu1[5], hi1[5], tu[5], ti[5];
    if (lane < 50) {
        #pragma unroll
        for (int a_ = 0; a_ < 5; ++a_) {
            float su = 0.f, si = 0.f;
            #pragma unroll
            for (int h = 0; h < 10; ++h) {
                su += Uproj[lane * 10 + h] * Ud[a_ * 10 + h];
                si += Iproj[lane * 10 + h] * Idd[a_ * 10 + h];
            }
            hu1[a_] = su; hi1[a_] = si;
        }
    } else {
        #pragma unroll
        for (int a_ = 0; a_ < 5; ++a_) { hu1[a_] = 0.f; hi1[a_] = 0.f; }
    }
    const float uw = (lane < 50) ? Uw[lane] : 0.f;
    const float iw = (lane < 50) ? Iw[lane] : 0.f;
    #pragma unroll
    for (int a_ = 0; a_ < 5; ++a_) {
        float hu = hu1[a_], hi = hi1[a_];
        #pragma unroll
        for (int c = 0; c < 5; ++c) {
            hu += hi1[c] * aff[a_ * 5 + c];   // Hu[e][a] += Hi1[e][c]*aff[a][c]
            hi += hu1[c] * aff[c * 5 + a_];   // Hi[e][c] += Hu1[e][a]*aff[a][c]
        }
        tu[a_] = uw * fmaxf(hu, 0.f);
        ti[a_] = iw * fmaxf(hi, 0.f);
    }
    #pragma unroll
    for (int a_ = 0; a_ < 5; ++a_) {
        #pragma unroll
        for (int o = 32; o; o >>= 1) {
            tu[a_] += __shfl_xor(tu[a_], o, 64);
            ti[a_] += __shfl_xor(ti[a_], o, 64);
        }
    }
    if (lane == 0) {
        float mu = tu[0], mi = ti[0];
        #pragma unroll
        for (int a_ = 1; a_ < 5; ++a_) { mu = fmaxf(mu, tu[a_]); mi = fmaxf(mi, ti[a_]); }
        float eu[5], ei[5], su = 0.f, si = 0.f;
        #pragma unroll
        for (int a_ = 0; a_ < 5; ++a_) {
            eu[a_] = expf(tu[a_] - mu); su += eu[a_];
            ei[a_] = expf(ti[a_] - mi); si += ei[a_];
        }
        float R = 0.f;
        #pragma unroll
        for (int a_ = 0; a_ < 5; ++a_) {
            float ar = 0.f;
            #pragma unroll
            for (int h = 0; h < 10; ++h) ar += Ud[a_ * 10 + h] * Idd[a_ * 10 + h];
            R += (eu[a_] / su) * (ei[a_] / si) * ar;
        }
        R += Bu[Uids[b]] + Bi[Iids[b]] + Bg[0];
        out[b] = R;
    }
}

extern "C" void kernel_launch(void* const* d_in, const int* in_sizes, int n_in,
                              void* d_out, int out_size, void* d_ws, size_t ws_size,
                              hipStream_t stream)
{
    const int*   Uids  = (const int*)d_in[0];
    const int*   Iids  = (const int*)d_in[1];
    const int*   Udocs = (const int*)d_in[2];
    const int*   Idocs = (const int*)d_in[3];
    const float* Wemb  = (const float*)d_in[4];
    const float* AE    = (const float*)d_in[5];
    const float* AP    = (const float*)d_in[6];
    const float* M     = (const float*)d_in[7];
    const float* Uproj = (const float*)d_in[8];
    const float* Uw    = (const float*)d_in[9];
    const float* Iproj = (const float*)d_in[10];
    const float* Iw    = (const float*)d_in[11];
    const float* Bu    = (const float*)d_in[12];
    const float* Bi    = (const float*)d_in[13];
    const float* Bg    = (const float*)d_in[14];

    float* Rep = (float*)d_ws;        // [2][256][5][10] = 102400 B
    float* out = (float*)d_out;

    const size_t smem = 15200 + 22000 + 2000;   // apS + adoc + lg = 39200 B
    k_aspect<<<2 * NB, 512, smem, stream>>>(Uids, Iids, Udocs, Idocs, Wemb, AE, AP, Rep);
    k_final<<<NB, 64, 0, stream>>>(Rep, Uids, Iids, M, Uproj, Uw, Iproj, Iw, Bu, Bi, Bg, out);
}

// Round 15
// 183.770 us; speedup vs baseline: 1.5868x; 1.3813x over previous
//
#include <hip/hip_runtime.h>

#define NA 5
#define LL 500
#define DD 300
#define H1 10
#define H2 50
#define NB 256
#define ADS 11   // adoc LDS row stride (odd -> conflict-free column access)

// One block per (side, batch): grid = 512, 256 threads. Thread t<250 owns
// TWO tokens (l=t, l=t+250), each with its own verbatim r9 accumulation
// chain -> one AP ds_read_b128 feeds 8 FMAs (was 4): per-CU LDS-pipe
// traffic halves (r14 analysis: 60K b128/CU on one pipe was the shared
// limiter; occupancy is grid/bitwise-capped at <=16 waves/CU anyway).
// AP staged in 2 K-passes (30.4 KB slice); LDS 54.4 KB -> 2 blocks/CU.

__global__ __launch_bounds__(256, 1)
void k_aspect(const int* __restrict__ Uids, const int* __restrict__ Iids,
              const int* __restrict__ Udocs, const int* __restrict__ Idocs,
              const float* __restrict__ Wemb,
              const float* __restrict__ AE,   // [A][30]
              const float* __restrict__ AP,   // [A][D][H1]
              float* __restrict__ Rep)        // [2][B][A][H1]
{
    extern __shared__ char smem[];
    float* apS = (float*)smem;                                  // 7600 f = 30400 B
    float (*adoc)[ADS] = (float(*)[ADS])(smem + 30400);         // 22000 B
    float* lg = (float*)(smem + 30400 + 22000);                 // 2000 B

    const int tid  = threadIdx.x;
    const int bid  = blockIdx.x;
    const int side = bid >> 8;
    const int b    = bid & 255;

    const int* ids  = side ? Iids : Uids;
    const int* docs = side ? Idocs : Udocs;

    const int uid = ids[b];
    const int* doc = docs + (long)uid * LL;

    // ---- phase 1: 2 tokens/thread, 50 channels each, registers only ----
    float accA[NA * H1], accB[NA * H1];
    #pragma unroll
    for (int c = 0; c < NA * H1; ++c) { accA[c] = 0.f; accB[c] = 0.f; }

    const bool act = (tid < 250);
    const float4* e4A = nullptr;
    const float4* e4B = nullptr;
    float4 a0, a1, b0, b1;
    a0 = a1 = b0 = b1 = make_float4(0.f, 0.f, 0.f, 0.f);
    if (act) {
        const int tokA = doc[tid];
        const int tokB = doc[tid + 250];
        e4A = (const float4*)(Wemb + (long)tokA * DD);
        e4B = (const float4*)(Wemb + (long)tokB * DD);
        a0 = e4A[0]; a1 = e4A[1];
        b0 = e4B[0]; b1 = e4B[1];
    }

    const int db0s[3] = {0, 38, 75};
    #pragma unroll
    for (int p = 0; p < 2; ++p) {
        const int db0 = db0s[p], db1 = db0s[p + 1];
        const int nf4 = (db1 - db0) * 10;          // float4 per aspect (380 or 370)

        __syncthreads();                            // previous slice fully consumed
        for (int i = tid; i < NA * 380; i += 256) { // stage slice
            const int a_ = i / 380, j = i - a_ * 380;
            if (j < nf4) {
                ((float4*)(apS + a_ * 1520))[j] =
                    ((const float4*)(AP + a_ * (DD * H1) + db0 * 40))[j];
            }
        }
        __syncthreads();

        if (act) {
            for (int db = db0; db < db1; ++db) {
                float4 a2 = a1, b2 = b1;
                if (db < 73) { a2 = e4A[db + 2]; b2 = e4B[db + 2]; }  // 2-deep prefetch
                const float av0 = a0.x, av1 = a0.y, av2 = a0.z, av3 = a0.w;
                const float bv0 = b0.x, bv1 = b0.y, bv2 = b0.z, bv3 = b0.w;
                const int o = (db - db0) * 40;
                #pragma unroll
                for (int a_ = 0; a_ < NA; ++a_) {
                    const float* wp = apS + a_ * 1520 + o;   // uniform -> ds broadcast
                    #pragma unroll
                    for (int h = 0; h < H1; ++h) {
                        const float w0 = wp[h], w1 = wp[H1 + h],
                                    w2 = wp[2 * H1 + h], w3 = wp[3 * H1 + h];
                        accA[a_ * H1 + h] += av0 * w0 + av1 * w1 + av2 * w2 + av3 * w3;
                        accB[a_ * H1 + h] += bv0 * w0 + bv1 * w1 + bv2 * w2 + bv3 * w3;
                    }
                }
                a0 = a1; a1 = a2;
                b0 = b1; b1 = b2;
            }
        }
    }

    // ---- phase 2: one aspect at a time through LDS (chains verbatim) ----
    #pragma unroll
    for (int a_ = 0; a_ < NA; ++a_) {
        __syncthreads();
        if (act) {
            #pragma unroll
            for (int h = 0; h < H1; ++h) {
                adoc[tid][h]       = accA[a_ * H1 + h];
                adoc[tid + 250][h] = accB[a_ * H1 + h];
            }
        }
        __syncthreads();

        // window logits (exact chain, strided by 256)
        for (int l = tid; l < LL; l += 256) {
            const float* aerow = AE + a_ * 30;      // uniform -> s_load (600 B, hot)
            float s = 0.f;
            if (l > 0) {
                const float* ad = &adoc[l - 1][0];
                #pragma unroll
                for (int h = 0; h < H1; ++h) s += ad[h] * aerow[h];
            }
            {
                const float* ad = &adoc[l][0];
                #pragma unroll
                for (int h = 0; h < H1; ++h) s += ad[h] * aerow[H1 + h];
            }
            if (l < LL - 1) {
                const float* ad = &adoc[l + 1][0];
                #pragma unroll
                for (int h = 0; h < H1; ++h) s += ad[h] * aerow[2 * H1 + h];
            }
            lg[l] = s;
        }
        __syncthreads();

        // softmax over L + weighted sum (wave 0; exact reduction)
        if (tid < 64) {
            const int lane = tid;
            float mx = -1e30f;
            for (int p = lane; p < LL; p += 64) mx = fmaxf(mx, lg[p]);
            #pragma unroll
            for (int o = 32; o; o >>= 1) mx = fmaxf(mx, __shfl_xor(mx, o, 64));
            float sum = 0.f;
            for (int p = lane; p < LL; p += 64) {
                float pr = expf(lg[p] - mx);
                lg[p] = pr;
                sum += pr;
            }
            #pragma unroll
            for (int o = 32; o; o >>= 1) sum += __shfl_xor(sum, o, 64);
            float r[H1];
            #pragma unroll
            for (int h = 0; h < H1; ++h) r[h] = 0.f;
            for (int p = lane; p < LL; p += 64) {
                const float pr = lg[p];
                const float* ad = &adoc[p][0];
                #pragma unroll
                for (int h = 0; h < H1; ++h) r[h] += pr * ad[h];
            }
            #pragma unroll
            for (int h = 0; h < H1; ++h) {
                #pragma unroll
                for (int o = 32; o; o >>= 1) r[h] += __shfl_xor(r[h], o, 64);
            }
            if (lane == 0) {
                const float inv = 1.f / sum;
                float* out = Rep + (((long)side * NB + b) * NA + a_) * H1;
                #pragma unroll
                for (int h = 0; h < H1; ++h) out[h] = r[h] * inv;
            }
        }
    }
}

__global__ __launch_bounds__(64)
void k_final(const float* __restrict__ Rep, const int* __restrict__ Uids,
             const int* __restrict__ Iids, const float* __restrict__ M,
             const float* __restrict__ Uproj, const float* __restrict__ Uw,
             const float* __restrict__ Iproj, const float* __restrict__ Iw,
             const float* __restrict__ Bu, const float* __restrict__ Bi,
             const float* __restrict__ Bg, float* __restrict__ out)
{
    __shared__ float Ud[50], Idd[50], tmp[50], aff[25];
    const int b = blockIdx.x, lane = threadIdx.x;
    if (lane < 50) {
        Ud[lane]  = Rep[(long)b * 50 + lane];
        Idd[lane] = Rep[(long)NB * 50 + (long)b * 50 + lane];
    }
    __syncthreads();
    if (lane < 50) {  // tmp[c][h] = sum_k M[h][k] * Id[c][k]
        const int c = lane / 10, h = lane % 10;
        float t = 0.f;
        #pragma unroll
        for (int k = 0; k < 10; ++k) t += M[h * 10 + k] * Idd[c * 10 + k];
        tmp[lane] = t;
    }
    __syncthreads();
    if (lane < 25) {  // aff[a][c] = relu(sum_h Ud[a][h] * tmp[c][h])
        const int a_ = lane / 5, c = lane % 5;
        float s = 0.f;
        #pragma unroll
        for (int h = 0; h < 10; ++h) s += Ud[a_ * 10 + h] * tmp[c * 10 + h];
        aff[lane] = fmaxf(s, 0.f);
    }
    __syncthreads();

    float hu1[5], hi1[5], tu[5], ti[5];
    if (lane < 50) {
        #pragma unroll
        for (int a_ = 0; a_ < 5; ++a_) {
            float su = 0.f, si = 0.f;
            #pragma unroll
            for (int h = 0; h < 10; ++h) {
                su += Uproj[lane * 10 + h] * Ud[a_ * 10 + h];
                si += Iproj[lane * 10 + h] * Idd[a_ * 10 + h];
            }
            hu1[a_] = su; hi1[a_] = si;
        }
    } else {
        #pragma unroll
        for (int a_ = 0; a_ < 5; ++a_) { hu1[a_] = 0.f; hi1[a_] = 0.f; }
    }
    const float uw = (lane < 50) ? Uw[lane] : 0.f;
    const float iw = (lane < 50) ? Iw[lane] : 0.f;
    #pragma unroll
    for (int a_ = 0; a_ < 5; ++a_) {
        float hu = hu1[a_], hi = hi1[a_];
        #pragma unroll
        for (int c = 0; c < 5; ++c) {
            hu += hi1[c] * aff[a_ * 5 + c];   // Hu[e][a] += Hi1[e][c]*aff[a][c]
            hi += hu1[c] * aff[c * 5 + a_];   // Hi[e][c] += Hu1[e][a]*aff[a][c]
        }
        tu[a_] = uw * fmaxf(hu, 0.f);
        ti[a_] = iw * fmaxf(hi, 0.f);
    }
    #pragma unroll
    for (int a_ = 0; a_ < 5; ++a_) {
        #pragma unroll
        for (int o = 32; o; o >>= 1) {
            tu[a_] += __shfl_xor(tu[a_], o, 64);
            ti[a_] += __shfl_xor(ti[a_], o, 64);
        }
    }
    if (lane == 0) {
        float mu = tu[0], mi = ti[0];
        #pragma unroll
        for (int a_ = 1; a_ < 5; ++a_) { mu = fmaxf(mu, tu[a_]); mi = fmaxf(mi, ti[a_]); }
        float eu[5], ei[5], su = 0.f, si = 0.f;
        #pragma unroll
        for (int a_ = 0; a_ < 5; ++a_) {
            eu[a_] = expf(tu[a_] - mu); su += eu[a_];
            ei[a_] = expf(ti[a_] - mi); si += ei[a_];
        }
        float R = 0.f;
        #pragma unroll
        for (int a_ = 0; a_ < 5; ++a_) {
            float ar = 0.f;
            #pragma unroll
            for (int h = 0; h < 10; ++h) ar += Ud[a_ * 10 + h] * Idd[a_ * 10 + h];
            R += (eu[a_] / su) * (ei[a_] / si) * ar;
        }
        R += Bu[Uids[b]] + Bi[Iids[b]] + Bg[0];
        out[b] = R;
    }
}

extern "C" void kernel_launch(void* const* d_in, const int* in_sizes, int n_in,
                              void* d_out, int out_size, void* d_ws, size_t ws_size,
                              hipStream_t stream)
{
    const int*   Uids  = (const int*)d_in[0];
    const int*   Iids  = (const int*)d_in[1];
    const int*   Udocs = (const int*)d_in[2];
    const int*   Idocs = (const int*)d_in[3];
    const float* Wemb  = (const float*)d_in[4];
    const float* AE    = (const float*)d_in[5];
    const float* AP    = (const float*)d_in[6];
    const float* M     = (const float*)d_in[7];
    const float* Uproj = (const float*)d_in[8];
    const float* Uw    = (const float*)d_in[9];
    const float* Iproj = (const float*)d_in[10];
    const float* Iw    = (const float*)d_in[11];
    const float* Bu    = (const float*)d_in[12];
    const float* Bi    = (const float*)d_in[13];
    const float* Bg    = (const float*)d_in[14];

    float* Rep = (float*)d_ws;        // [2][256][5][10] = 102400 B
    float* out = (float*)d_out;

    const size_t smem = 30400 + 22000 + 2000;   // apS + adoc + lg = 54400 B
    k_aspect<<<2 * NB, 256, smem, stream>>>(Uids, Iids, Udocs, Idocs, Wemb, AE, AP, Rep);
    k_final<<<NB, 64, 0, stream>>>(Rep, Uids, Iids, M, Uproj, Uw, Iproj, Iw, Bu, Bi, Bg, out);
}

// Round 16
// 156.218 us; speedup vs baseline: 1.8667x; 1.1764x over previous
//
#include <hip/hip_runtime.h>

#define NA 5
#define LL 500
#define DD 300
#define H1 10
#define H2 50
#define NB 256
#define ADS 11   // adoc LDS row stride (odd -> conflict-free column access)

// One block per (side, batch): grid = 512, 256 threads, 2 tokens/thread
// (r15 structure). ROUND-16 CHANGE: inner-loop AP reads forced to
// ds_read_b128 — per (db, aspect) the 40-float slice is bulk-loaded into a
// statically-indexed w[40] (SROA -> registers), then the identical FMA
// expressions read w[h], w[10+h], w[20+h], w[30+h]. LDS ops/iter drop 4x
// (r15 analysis: scalar b32 reads saturated the shared per-CU LDS pipe at
// ~1600 ops/iter-period, pinning VALU at 49%). Bitwise-identical chains.

__global__ __launch_bounds__(256, 1)
void k_aspect(const int* __restrict__ Uids, const int* __restrict__ Iids,
              const int* __restrict__ Udocs, const int* __restrict__ Idocs,
              const float* __restrict__ Wemb,
              const float* __restrict__ AE,   // [A][30]
              const float* __restrict__ AP,   // [A][D][H1]
              float* __restrict__ Rep)        // [2][B][A][H1]
{
    extern __shared__ char smem[];
    float* apS = (float*)smem;                                  // 7600 f = 30400 B
    float (*adoc)[ADS] = (float(*)[ADS])(smem + 30400);         // 22000 B
    float* lg = (float*)(smem + 30400 + 22000);                 // 2000 B

    const int tid  = threadIdx.x;
    const int bid  = blockIdx.x;
    const int side = bid >> 8;
    const int b    = bid & 255;

    const int* ids  = side ? Iids : Uids;
    const int* docs = side ? Idocs : Udocs;

    const int uid = ids[b];
    const int* doc = docs + (long)uid * LL;

    // ---- phase 1: 2 tokens/thread, 50 channels each, registers only ----
    float accA[NA * H1], accB[NA * H1];
    #pragma unroll
    for (int c = 0; c < NA * H1; ++c) { accA[c] = 0.f; accB[c] = 0.f; }

    const bool act = (tid < 250);
    const float4* e4A = nullptr;
    const float4* e4B = nullptr;
    float4 a0, a1, b0, b1;
    a0 = a1 = b0 = b1 = make_float4(0.f, 0.f, 0.f, 0.f);
    if (act) {
        const int tokA = doc[tid];
        const int tokB = doc[tid + 250];
        e4A = (const float4*)(Wemb + (long)tokA * DD);
        e4B = (const float4*)(Wemb + (long)tokB * DD);
        a0 = e4A[0]; a1 = e4A[1];
        b0 = e4B[0]; b1 = e4B[1];
    }

    const int db0s[3] = {0, 38, 75};
    #pragma unroll
    for (int p = 0; p < 2; ++p) {
        const int db0 = db0s[p], db1 = db0s[p + 1];
        const int nf4 = (db1 - db0) * 10;          // float4 per aspect (380 or 370)

        __syncthreads();                            // previous slice fully consumed
        for (int i = tid; i < NA * 380; i += 256) { // stage slice
            const int a_ = i / 380, j = i - a_ * 380;
            if (j < nf4) {
                ((float4*)(apS + a_ * 1520))[j] =
                    ((const float4*)(AP + a_ * (DD * H1) + db0 * 40))[j];
            }
        }
        __syncthreads();

        if (act) {
            for (int db = db0; db < db1; ++db) {
                float4 a2 = a1, b2 = b1;
                if (db < 73) { a2 = e4A[db + 2]; b2 = e4B[db + 2]; }  // 2-deep prefetch
                const float av0 = a0.x, av1 = a0.y, av2 = a0.z, av3 = a0.w;
                const float bv0 = b0.x, bv1 = b0.y, bv2 = b0.z, bv3 = b0.w;
                const int o = (db - db0) * 40;
                #pragma unroll
                for (int a_ = 0; a_ < NA; ++a_) {
                    // bulk b128 load of the 40-float slice -> registers
                    const float4* wp4 = (const float4*)(apS + a_ * 1520 + o);
                    float w[40];
                    #pragma unroll
                    for (int j = 0; j < 10; ++j)
                        *reinterpret_cast<float4*>(&w[4 * j]) = wp4[j];
                    #pragma unroll
                    for (int h = 0; h < H1; ++h) {
                        const float w0 = w[h], w1 = w[10 + h],
                                    w2 = w[20 + h], w3 = w[30 + h];
                        accA[a_ * H1 + h] += av0 * w0 + av1 * w1 + av2 * w2 + av3 * w3;
                        accB[a_ * H1 + h] += bv0 * w0 + bv1 * w1 + bv2 * w2 + bv3 * w3;
                    }
                }
                a0 = a1; a1 = a2;
                b0 = b1; b1 = b2;
            }
        }
    }

    // ---- phase 2: one aspect at a time through LDS (chains verbatim) ----
    #pragma unroll
    for (int a_ = 0; a_ < NA; ++a_) {
        __syncthreads();
        if (act) {
            #pragma unroll
            for (int h = 0; h < H1; ++h) {
                adoc[tid][h]       = accA[a_ * H1 + h];
                adoc[tid + 250][h] = accB[a_ * H1 + h];
            }
        }
        __syncthreads();

        // window logits (exact chain, strided by 256)
        for (int l = tid; l < LL; l += 256) {
            const float* aerow = AE + a_ * 30;      // uniform -> s_load (600 B, hot)
            float s = 0.f;
            if (l > 0) {
                const float* ad = &adoc[l - 1][0];
                #pragma unroll
                for (int h = 0; h < H1; ++h) s += ad[h] * aerow[h];
            }
            {
                const float* ad = &adoc[l][0];
                #pragma unroll
                for (int h = 0; h < H1; ++h) s += ad[h] * aerow[H1 + h];
            }
            if (l < LL - 1) {
                const float* ad = &adoc[l + 1][0];
                #pragma unroll
                for (int h = 0; h < H1; ++h) s += ad[h] * aerow[2 * H1 + h];
            }
            lg[l] = s;
        }
        __syncthreads();

        // softmax over L + weighted sum (wave 0; exact reduction)
        if (tid < 64) {
            const int lane = tid;
            float mx = -1e30f;
            for (int p = lane; p < LL; p += 64) mx = fmaxf(mx, lg[p]);
            #pragma unroll
            for (int o = 32; o; o >>= 1) mx = fmaxf(mx, __shfl_xor(mx, o, 64));
            float sum = 0.f;
            for (int p = lane; p < LL; p += 64) {
                float pr = expf(lg[p] - mx);
                lg[p] = pr;
                sum += pr;
            }
            #pragma unroll
            for (int o = 32; o; o >>= 1) sum += __shfl_xor(sum, o, 64);
            float r[H1];
            #pragma unroll
            for (int h = 0; h < H1; ++h) r[h] = 0.f;
            for (int p = lane; p < LL; p += 64) {
                const float pr = lg[p];
                const float* ad = &adoc[p][0];
                #pragma unroll
                for (int h = 0; h < H1; ++h) r[h] += pr * ad[h];
            }
            #pragma unroll
            for (int h = 0; h < H1; ++h) {
                #pragma unroll
                for (int o = 32; o; o >>= 1) r[h] += __shfl_xor(r[h], o, 64);
            }
            if (lane == 0) {
                const float inv = 1.f / sum;
                float* out = Rep + (((long)side * NB + b) * NA + a_) * H1;
                #pragma unroll
                for (int h = 0; h < H1; ++h) out[h] = r[h] * inv;
            }
        }
    }
}

__global__ __launch_bounds__(64)
void k_final(const float* __restrict__ Rep, const int* __restrict__ Uids,
             const int* __restrict__ Iids, const float* __restrict__ M,
             const float* __restrict__ Uproj, const float* __restrict__ Uw,
             const float* __restrict__ Iproj, const float* __restrict__ Iw,
             const float* __restrict__ Bu, const float* __restrict__ Bi,
             const float* __restrict__ Bg, float* __restrict__ out)
{
    __shared__ float Ud[50], Idd[50], tmp[50], aff[25];
    const int b = blockIdx.x, lane = threadIdx.x;
    if (lane < 50) {
        Ud[lane]  = Rep[(long)b * 50 + lane];
        Idd[lane] = Rep[(long)NB * 50 + (long)b * 50 + lane];
    }
    __syncthreads();
    if (lane < 50) {  // tmp[c][h] = sum_k M[h][k] * Id[c][k]
        const int c = lane / 10, h = lane % 10;
        float t = 0.f;
        #pragma unroll
        for (int k = 0; k < 10; ++k) t += M[h * 10 + k] * Idd[c * 10 + k];
        tmp[lane] = t;
    }
    __syncthreads();
    if (lane < 25) {  // aff[a][c] = relu(sum_h Ud[a][h] * tmp[c][h])
        const int a_ = lane / 5, c = lane % 5;
        float s = 0.f;
        #pragma unroll
        for (int h = 0; h < 10; ++h) s += Ud[a_ * 10 + h] * tmp[c * 10 + h];
        aff[lane] = fmaxf(s, 0.f);
    }
    __syncthreads();

    float hu1[5], hi1[5], tu[5], ti[5];
    if (lane < 50) {
        #pragma unroll
        for (int a_ = 0; a_ < 5; ++a_) {
            float su = 0.f, si = 0.f;
            #pragma unroll
            for (int h = 0; h < 10; ++h) {
                su += Uproj[lane * 10 + h] * Ud[a_ * 10 + h];
                si += Iproj[lane * 10 + h] * Idd[a_ * 10 + h];
            }
            hu1[a_] = su; hi1[a_] = si;
        }
    } else {
        #pragma unroll
        for (int a_ = 0; a_ < 5; ++a_) { hu1[a_] = 0.f; hi1[a_] = 0.f; }
    }
    const float uw = (lane < 50) ? Uw[lane] : 0.f;
    const float iw = (lane < 50) ? Iw[lane] : 0.f;
    #pragma unroll
    for (int a_ = 0; a_ < 5; ++a_) {
        float hu = hu1[a_], hi = hi1[a_];
        #pragma unroll
        for (int c = 0; c < 5; ++c) {
            hu += hi1[c] * aff[a_ * 5 + c];   // Hu[e][a] += Hi1[e][c]*aff[a][c]
            hi += hu1[c] * aff[c * 5 + a_];   // Hi[e][c] += Hu1[e][a]*aff[a][c]
        }
        tu[a_] = uw * fmaxf(hu, 0.f);
        ti[a_] = iw * fmaxf(hi, 0.f);
    }
    #pragma unroll
    for (int a_ = 0; a_ < 5; ++a_) {
        #pragma unroll
        for (int o = 32; o; o >>= 1) {
            tu[a_] += __shfl_xor(tu[a_], o, 64);
            ti[a_] += __shfl_xor(ti[a_], o, 64);
        }
    }
    if (lane == 0) {
        float mu = tu[0], mi = ti[0];
        #pragma unroll
        for (int a_ = 1; a_ < 5; ++a_) { mu = fmaxf(mu, tu[a_]); mi = fmaxf(mi, ti[a_]); }
        float eu[5], ei[5], su = 0.f, si = 0.f;
        #pragma unroll
        for (int a_ = 0; a_ < 5; ++a_) {
            eu[a_] = expf(tu[a_] - mu); su += eu[a_];
            ei[a_] = expf(ti[a_] - mi); si += ei[a_];
        }
        float R = 0.f;
        #pragma unroll
        for (int a_ = 0; a_ < 5; ++a_) {
            float ar = 0.f;
            #pragma unroll
            for (int h = 0; h < 10; ++h) ar += Ud[a_ * 10 + h] * Idd[a_ * 10 + h];
            R += (eu[a_] / su) * (ei[a_] / si) * ar;
        }
        R += Bu[Uids[b]] + Bi[Iids[b]] + Bg[0];
        out[b] = R;
    }
}

extern "C" void kernel_launch(void* const* d_in, const int* in_sizes, int n_in,
                              void* d_out, int out_size, void* d_ws, size_t ws_size,
                              hipStream_t stream)
{
    const int*   Uids  = (const int*)d_in[0];
    const int*   Iids  = (const int*)d_in[1];
    const int*   Udocs = (const int*)d_in[2];
    const int*   Idocs = (const int*)d_in[3];
    const float* Wemb  = (const float*)d_in[4];
    const float* AE    = (const float*)d_in[5];
    const float* AP    = (const float*)d_in[6];
    const float* M     = (const float*)d_in[7];
    const float* Uproj = (const float*)d_in[8];
    const float* Uw    = (const float*)d_in[9];
    const float* Iproj = (const float*)d_in[10];
    const float* Iw    = (const float*)d_in[11];
    const float* Bu    = (const float*)d_in[12];
    const float* Bi    = (const float*)d_in[13];
    const float* Bg    = (const float*)d_in[14];

    float* Rep = (float*)d_ws;        // [2][256][5][10] = 102400 B
    float* out = (float*)d_out;

    const size_t smem = 30400 + 22000 + 2000;   // apS + adoc + lg = 54400 B
    k_aspect<<<2 * NB, 256, smem, stream>>>(Uids, Iids, Udocs, Idocs, Wemb, AE, AP, Rep);
    k_final<<<NB, 64, 0, stream>>>(Rep, Uids, Iids, M, Uproj, Uw, Iproj, Iw, Bu, Bi, Bg, out);
}